// Round 1
// baseline (986.174 us; speedup 1.0000x reference)
//
#include <hip/hip_runtime.h>

#define SEQ 2048
#define HID 1024
#define KCAT 2048                 // hi|lo concatenated K
#define SZ (SEQ * HID)            // elements per theta level = 2097152

typedef unsigned short u16;
typedef __attribute__((ext_vector_type(8))) short short8;
typedef __attribute__((ext_vector_type(4))) float floatx4;

#define MODE_SHIFT    1           // A row s reads row s-1 (s==0 -> stateRow)
#define MODE_OUTF_RAW 2           // outF gets pre-tanh value (PRE0 stage)

// bf16 helpers via raw bit ops (round-to-nearest-even); avoids header type issues
__device__ __forceinline__ u16 f2b(float v) {
    unsigned x = __builtin_bit_cast(unsigned, v);
    unsigned r = (x + 0x7fffu + ((x >> 16) & 1u)) >> 16;
    return (u16)r;
}
__device__ __forceinline__ float b2f(u16 u) {
    return __builtin_bit_cast(float, ((unsigned)u) << 16);
}

// f32 [rows,K] -> bf16 pair [rows, 2K] as [hi(K) | lo(K)] per row
__global__ void cvt_pair(const float* __restrict__ src, u16* __restrict__ dst,
                         int total, int K) {
    int i = blockIdx.x * 256 + threadIdx.x;
    if (i >= total) return;
    int r = i / K, k = i - r * K;
    float v = src[i];
    u16 hi = f2b(v);
    u16 lo = f2b(v - b2f(hi));
    size_t base = (size_t)r * (2 * K);
    dst[base + k] = hi;
    dst[base + K + k] = lo;
}

// C[s][n] = sum_k Ashift[s][k] * B[n][k]  (A,B bf16, f32 accumulate)
// epilogue: v = dot + addA[s][n] + addB[s][n] + b1[n] + b2[n]; t = tanh(v)
//   outF[s][n]  = (mode&RAW) ? v : t      (if outF)
//   outCat[s][.] = bf16 pair of t         (if outCat)  layout [s][2*HID]
__launch_bounds__(256, 2)
__global__ void gemm64(const u16* __restrict__ A, const u16* __restrict__ stateRow,
                       const u16* __restrict__ B,
                       const float* __restrict__ addA, const float* __restrict__ addB,
                       const float* __restrict__ b1, const float* __restrict__ b2,
                       float* __restrict__ outF, u16* __restrict__ outCat,
                       int Klen, int mode) {
    __shared__ u16 As[64 * 32];
    __shared__ u16 Bs[64 * 32];
    const int tid  = threadIdx.x;
    const int lane = tid & 63, wave = tid >> 6;
    const int wr = wave >> 1, wc = wave & 1;          // 2x2 waves over 64x64
    const int quad = lane >> 4, l16 = lane & 15;
    const int rowBase = blockIdx.y * 64, colBase = blockIdx.x * 64;

    floatx4 acc[2][2];
    #pragma unroll
    for (int mi = 0; mi < 2; mi++)
        #pragma unroll
        for (int ni = 0; ni < 2; ni++)
            acc[mi][ni] = (floatx4){0.f, 0.f, 0.f, 0.f};

    // staging: each thread one 16B chunk per operand per K-tile
    const int sr = tid >> 2;              // 0..63 tile row
    const int sk = (tid & 3) * 8;         // 0,8,16,24
    const int ga = rowBase + sr;
    const u16* aRow;
    if (mode & MODE_SHIFT)
        aRow = (ga == 0) ? stateRow : (A + (size_t)(ga - 1) * KCAT);
    else
        aRow = A + (size_t)ga * KCAT;
    const u16* bRow = B + (size_t)(colBase + sr) * KCAT;

    for (int kb = 0; kb < Klen; kb += 32) {
        *(short8*)&As[tid * 8] = *(const short8*)(aRow + kb + sk);
        *(short8*)&Bs[tid * 8] = *(const short8*)(bRow + kb + sk);
        __syncthreads();
        short8 a0 = *(const short8*)&As[(wr * 32 + 0 * 16 + l16) * 32 + quad * 8];
        short8 a1 = *(const short8*)&As[(wr * 32 + 1 * 16 + l16) * 32 + quad * 8];
        short8 b0 = *(const short8*)&Bs[(wc * 32 + 0 * 16 + l16) * 32 + quad * 8];
        short8 b1v = *(const short8*)&Bs[(wc * 32 + 1 * 16 + l16) * 32 + quad * 8];
        acc[0][0] = __builtin_amdgcn_mfma_f32_16x16x32_bf16(a0, b0, acc[0][0], 0, 0, 0);
        acc[0][1] = __builtin_amdgcn_mfma_f32_16x16x32_bf16(a0, b1v, acc[0][1], 0, 0, 0);
        acc[1][0] = __builtin_amdgcn_mfma_f32_16x16x32_bf16(a1, b0, acc[1][0], 0, 0, 0);
        acc[1][1] = __builtin_amdgcn_mfma_f32_16x16x32_bf16(a1, b1v, acc[1][1], 0, 0, 0);
        __syncthreads();
    }

    #pragma unroll
    for (int mi = 0; mi < 2; mi++) {
        #pragma unroll
        for (int ni = 0; ni < 2; ni++) {
            const int col = colBase + wc * 32 + ni * 16 + l16;
            #pragma unroll
            for (int i = 0; i < 4; i++) {
                const int row = rowBase + wr * 32 + mi * 16 + quad * 4 + i;
                const size_t idx = (size_t)row * HID + col;
                float v = acc[mi][ni][i];
                if (addA) v += addA[idx];
                if (addB) v += addB[idx];
                if (b1) v += b1[col] + b2[col];
                const float t = tanhf(v);
                if (outF) outF[idx] = (mode & MODE_OUTF_RAW) ? v : t;
                if (outCat) {
                    u16 hi = f2b(t);
                    u16 lo = f2b(t - b2f(hi));
                    outCat[(size_t)row * KCAT + col] = hi;
                    outCat[(size_t)row * KCAT + HID + col] = lo;
                }
            }
        }
    }
}

__global__ void tail_copy(float* __restrict__ out) {
    int t = blockIdx.x * 256 + threadIdx.x;
    if (t < HID) out[(size_t)8 * SZ + t] = out[(size_t)2047 * HID + t];
}

extern "C" void kernel_launch(void* const* d_in, const int* in_sizes, int n_in,
                              void* d_out, int out_size, void* d_ws, size_t ws_size,
                              hipStream_t stream) {
    const float* x        = (const float*)d_in[0];   // [1,2048,1024]
    const float* internal = (const float*)d_in[1];   // [8,2048,1024]
    const float* state    = (const float*)d_in[2];   // [1,1,1024]
    const float* W_ih     = (const float*)d_in[3];   // [1024,1024]
    const float* W_hh     = (const float*)d_in[4];   // [1024,1024]
    const float* b_ih     = (const float*)d_in[5];   // [1024]
    const float* b_hh     = (const float*)d_in[6];   // [1024]
    float* out = (float*)d_out;
    char* ws = (char*)d_ws;

    u16*   WihC = (u16*)(ws);                        //  4 MB  [1024][2048]
    u16*   WhhC = (u16*)(ws + ((size_t)4 << 20));    //  4 MB  [1024][2048]
    u16*   XC   = (u16*)(ws + ((size_t)8 << 20));    //  8 MB  [2048][2048]
    u16*   H0   = (u16*)(ws + ((size_t)16 << 20));   //  8 MB  [2048][2048]
    u16*   H1   = (u16*)(ws + ((size_t)24 << 20));   //  8 MB  [2048][2048]
    float* PRE0 = (float*)(ws + ((size_t)32 << 20)); //  8 MB  [2048][1024]
    u16*   SC   = (u16*)(ws + ((size_t)40 << 20));   //  4 KB  [2048]

    // operand conversion (hi|lo bf16 pairs)
    cvt_pair<<<(1024 * 1024 + 255) / 256, 256, 0, stream>>>(W_ih, WihC, 1024 * 1024, 1024);
    cvt_pair<<<(1024 * 1024 + 255) / 256, 256, 0, stream>>>(W_hh, WhhC, 1024 * 1024, 1024);
    cvt_pair<<<(SEQ * 1024 + 255) / 256, 256, 0, stream>>>(x, XC, SEQ * 1024, 1024);
    cvt_pair<<<(1024 + 255) / 256, 256, 0, stream>>>(state, SC, 1024, 1024);

    dim3 grid(HID / 64, SEQ / 64); // (16, 32)

    // stage 0: PRE0 = x@W_ih^T + internal[0] + b_ih + b_hh ;  H^0 = tanh(PRE0)
    gemm64<<<grid, 256, 0, stream>>>(XC, nullptr, WihC, nullptr, internal,
                                     b_ih, b_hh, PRE0, H0, KCAT, MODE_OUTF_RAW);

    // base chain via Jacobi sweeps: H[s] = tanh(PRE0[s] + W_hh * H[s-1])
    u16* cur = H0; u16* nxt = H1;
    const int k1 = 14;  // cheap sweeps, hi-only K=1024
    const int k2 = 6;   // polish sweeps, full split K=2048
    for (int i = 0; i < k1 + k2; i++) {
        const bool last = (i == k1 + k2 - 1);
        const int klen = (i < k1) ? 1024 : KCAT;
        gemm64<<<grid, 256, 0, stream>>>(cur, SC, WhhC, PRE0, nullptr, nullptr, nullptr,
                                         last ? out : nullptr, nxt, klen, MODE_SHIFT);
        u16* t = cur; cur = nxt; nxt = t;
    }

    // theta levels: G_th[s] = tanh(internal[th][s] + b + W_hh * G_{th-1}[s])
    for (int th = 1; th <= 7; th++) {
        gemm64<<<grid, 256, 0, stream>>>(cur, nullptr, WhhC, nullptr,
                                         internal + (size_t)th * SZ,
                                         b_ih, b_hh, out + (size_t)th * SZ, nxt, KCAT, 0);
        u16* t = cur; cur = nxt; nxt = t;
    }

    // hT = base chain's last state
    tail_copy<<<4, 256, 0, stream>>>(out);
}